// Round 10
// baseline (209.782 us; speedup 1.0000x reference)
//
#include <hip/hip_runtime.h>

// Problem constants (from reference)
#define N_PTS 8388608
#define FX 758.03967f
#define CXC 621.46572f
#define FY 761.62359f
#define CYC 756.86402f
#define U_MAX 1231.0f   // WIDTH - 1
#define W_MAX 1615.0f   // HEIGHT - 1
#define MIN_D 1.0f
#define MAX_D_R 10.0f
#define MAX_D_M 5.0f

#define THREADS 256
#define BLOCKS 2048              // 8 blocks/CU -> fully resident (persistent)
#define N_UNITS (N_PTS / 4)      // one unit = 4 points = 3 float4; 2,097,152 units

// Workspace layout (uints): [16 + b] (b in [0,BLOCKS)) = per-block partial count,
// written by PLAIN STORE (no atomics, no pre-zero needed -> no init kernel).
//
// Evidence ledger (frustum dur / hbm_bytes / eff BW):
//  R5 strided x3:      62.0us / 152MB / 2.45   R6 LDS-coalesced: 58.5 / 151 / 2.59
//  R7 strided x6:      86.8us / 209MB / 2.41 (96B-lane-stride stores broke L2
//     merging: RMW fills + double writebacks -- traffic grew, BW slope same)
//  R8 R6+nt stores:    59.6us / 151MB / 2.54 (WRITE clean: nt safe on full lines;
//     FETCH unchanged -> L3-residency lever dead, poison fills cycle L3)
//  R9 R6 depth x2:     60.3us / 151MB / 2.51 (2x in-flight, occ 45%, null)
//  => 5 independent levers null; dur == bytes / ~2.5 TB/s invariant.
//     In-flight math: need ~1.2MB, have ~16MB -> latency-depth exonerated.
//  THIS ROUND: last structural discriminator -- persistent grid-stride waves
//  (copy-ubench structure: loop pipelines next loads past prior stores) +
//  per-block pose (R4-proven safe; R4's 571us was threadfence+ticket, counters
//  showed same bytes + VALU 2.7% = stall storm) + atomic-free count slots
//  (2 kernels total).
//  R3: nt on 48B-strided stores amplified WRITE 1.74x. Plain cached stores.

__global__ __launch_bounds__(256) void frustum_kernel(const float4* __restrict__ pts,
                                                      const float* __restrict__ x,
                                                      const float* __restrict__ y,
                                                      const float* __restrict__ z,
                                                      const float* __restrict__ roll,
                                                      const float* __restrict__ pitch,
                                                      const float* __restrict__ yaw,
                                                      float* __restrict__ ws,
                                                      float4* __restrict__ out) {
    // Per-block pose setup (bit-identical expressions to the old pose_setup_kernel).
    __shared__ float S[12];
    if (threadIdx.x == 0) {
        float cr = cosf(*roll), sr = sinf(*roll);
        float cp = cosf(*pitch), sp = sinf(*pitch);
        float cy = cosf(*yaw),  sy = sinf(*yaw);
        // R = Rx(roll) @ Ry(pitch) @ Rz(yaw), row-major. At the zero pose this is
        // exactly identity (with signed zeros), so v = points bit-exact.
        S[0] = cp * cy;                S[1] = -(cp * sy);             S[2] = sp;
        S[3] = cr * sy + sr * sp * cy; S[4] = cr * cy - sr * sp * sy; S[5] = -(sr * cp);
        S[6] = sr * sy - cr * sp * cy; S[7] = sr * cy + cr * sp * sy; S[8] = cr * cp;
        S[9] = *x; S[10] = *y; S[11] = *z;
    }
    __syncthreads();

    const float R0 = S[0], R1 = S[1], R2 = S[2];
    const float R3 = S[3], R4 = S[4], R5 = S[5];
    const float R6 = S[6], R7 = S[7], R8 = S[8];
    const float t0 = S[9], t1 = S[10], t2 = S[11];

    int cnt = 0;
    auto proc = [&](float px, float py, float pz, float& ox, float& oy, float& oz) {
        float d0 = px - t0, d1 = py - t1, d2 = pz - t2;
        // ascending-k fma accumulation to match the numpy reference's matmul
        float v0 = fmaf(d2, R6, fmaf(d1, R3, d0 * R0));
        float v1 = fmaf(d2, R7, fmaf(d1, R4, d0 * R1));
        float v2 = fmaf(d2, R8, fmaf(d1, R5, d0 * R2));
        float p0 = fmaf(v2, CXC, v0 * FX);
        float p1 = fmaf(v2, CYC, v1 * FY);
        float u = p0 / v2;           // IEEE div; inf/nan on v2==0 compares false, same as numpy mask
        float w = p1 / v2;
        bool fov = (v2 > 0.0f) && (u > 1.0f) && (u < U_MAX) && (w > 1.0f) && (w < W_MAX);
        if (fov && (v2 > MIN_D) && (v2 < MAX_D_R)) cnt++;
        bool m = fov && (v2 > MIN_D) && (v2 < MAX_D_M);
        ox = m ? v0 : 0.0f;
        oy = m ? v1 : 0.0f;
        oz = m ? v2 : 0.0f;
    };

    // Persistent grid-stride loop: 4 units/thread, stride 24 MB. __restrict__
    // lets the compiler hoist iteration i+1's loads above iteration i's stores
    // (steady-state load/store overlap, copy-ubench style).
    const int stride = BLOCKS * THREADS;
    for (int unit = blockIdx.x * THREADS + threadIdx.x; unit < N_UNITS; unit += stride) {
        const long base = (long)unit * 3;
        float4 q0 = pts[base + 0];
        float4 q1 = pts[base + 1];
        float4 q2 = pts[base + 2];

        float4 o0, o1, o2;
        proc(q0.x, q0.y, q0.z, o0.x, o0.y, o0.z);   // point 0
        proc(q0.w, q1.x, q1.y, o0.w, o1.x, o1.y);   // point 1
        proc(q1.z, q1.w, q2.x, o1.z, o1.w, o2.x);   // point 2
        proc(q2.y, q2.z, q2.w, o2.y, o2.z, o2.w);   // point 3

        out[base + 0] = o0;
        out[base + 1] = o1;
        out[base + 2] = o2;
    }

    // wave reduce (wave = 64), then block reduce in LDS, then ONE PLAIN STORE
    // per block into its own slot (no atomics -> no zero-init dependency).
    for (int off = 32; off > 0; off >>= 1) cnt += __shfl_down(cnt, off, 64);
    __shared__ int red[4];
    const int wave = threadIdx.x >> 6;
    if ((threadIdx.x & 63) == 0) red[wave] = cnt;
    __syncthreads();
    if (threadIdx.x == 0) {
        int s = red[0] + red[1] + red[2] + red[3];
        ((unsigned int*)ws)[16 + blockIdx.x] = (unsigned int)s;   // unconditional: ws is poisoned
    }
}

__global__ void finalize_kernel(const float* __restrict__ ws, float* __restrict__ out) {
    const unsigned int* slots = (const unsigned int*)ws + 16;
    unsigned int c = 0;
    for (int i = threadIdx.x; i < BLOCKS; i += 256) c += slots[i];
    for (int off = 32; off > 0; off >>= 1) c += __shfl_down(c, off, 64);
    __shared__ unsigned int red[4];
    const int wave = threadIdx.x >> 6;
    if ((threadIdx.x & 63) == 0) red[wave] = c;
    __syncthreads();
    if (threadIdx.x == 0) {
        unsigned int tot = red[0] + red[1] + red[2] + red[3];
        out[(long)3 * N_PTS] = 1.0f / ((float)tot + 1e-6f);
    }
}

extern "C" void kernel_launch(void* const* d_in, const int* in_sizes, int n_in,
                              void* d_out, int out_size, void* d_ws, size_t ws_size,
                              hipStream_t stream) {
    const float* points = (const float*)d_in[0];
    const float* x      = (const float*)d_in[1];
    const float* y      = (const float*)d_in[2];
    const float* z      = (const float*)d_in[3];
    const float* roll   = (const float*)d_in[4];
    const float* pitch  = (const float*)d_in[5];
    const float* yaw    = (const float*)d_in[6];
    float* ws = (float*)d_ws;
    float* out = (float*)d_out;

    frustum_kernel<<<BLOCKS, THREADS, 0, stream>>>((const float4*)points,
                                                   x, y, z, roll, pitch, yaw,
                                                   ws, (float4*)out);
    finalize_kernel<<<1, 256, 0, stream>>>(ws, out);
}

// Round 11
// 196.701 us; speedup vs baseline: 1.0665x; 1.0665x over previous
//
#include <hip/hip_runtime.h>

// Problem constants (from reference)
#define N_PTS 8388608
#define FX 758.03967f
#define CXC 621.46572f
#define FY 761.62359f
#define CYC 756.86402f
#define U_MAX 1231.0f   // WIDTH - 1
#define W_MAX 1615.0f   // HEIGHT - 1
#define MIN_D 1.0f
#define MAX_D_R 10.0f
#define MAX_D_M 5.0f

#define THREADS 256
#define BLOCKS (N_PTS / 1024)    // 1024 points per block -> 8192 blocks

// Workspace layout (uints): [16 + b] (b in [0,BLOCKS)) = per-block partial
// count, PLAIN STORE (no atomics, no zero-init -> no init kernel needed).
//
// Evidence ledger (frustum dur / hbm_bytes / eff BW):
//  R5 strided x3:    62.0 / 152MB / 2.45    R6 LDS-coalesced: 58.5 / 151 / 2.59
//  R7 strided x6:    86.8 / 209MB / 2.41    R8 R6+nt stores:  59.6 / 151 / 2.54
//  R9 R6 depth x2:   60.3 / 151MB / 2.51    R10 persistent:   77.5 / 203 / 2.62
//  => SIX independent levers null/negative (store policy, coalescing, lane
//     stride, wave depth, occupancy, persistent pipelining). Every variant
//     streams at 2.4-2.6 TB/s; dur == hbm_bytes / 2.5 TB/s invariant.
//     bench_total == frustum + ~133us (harness poison fills 2x60us + launches).
//  THIS ROUND: revert memory path to R6 exactly (best measured) + bank the
//  R10-verified overhead cuts: per-block pose (R4's 571us was the
//  threadfence/ticket, NOT the pose; R10 passed with per-block pose) and
//  per-block plain-store slots -> 2 kernels total.
//  R3: nt on 48B-strided stores amplified WRITE 1.74x. Plain cached stores.

__global__ __launch_bounds__(256) void frustum_kernel(const float4* __restrict__ pts,
                                                      const float* __restrict__ x,
                                                      const float* __restrict__ y,
                                                      const float* __restrict__ z,
                                                      const float* __restrict__ roll,
                                                      const float* __restrict__ pitch,
                                                      const float* __restrict__ yaw,
                                                      float* __restrict__ ws,
                                                      float4* __restrict__ out) {
    // 256 threads x 4 points = 1024 points = 768 float4 = 12 KB per block.
    __shared__ float4 st[768];
    __shared__ float S[12];

    const int t = threadIdx.x;
    const long gbase = (long)blockIdx.x * 768;   // block's first float4 index

    // Coalesced stage-in: lane-contiguous 16B, 3 fully-dense 1KB wave loads.
    st[t]       = pts[gbase + t];
    st[t + 256] = pts[gbase + t + 256];
    st[t + 512] = pts[gbase + t + 512];

    // Per-block pose setup (bit-identical expressions to the old
    // pose_setup_kernel; R10-verified). Hidden under the staging loads.
    if (t == 0) {
        float cr = cosf(*roll), sr = sinf(*roll);
        float cp = cosf(*pitch), sp = sinf(*pitch);
        float cy = cosf(*yaw),  sy = sinf(*yaw);
        // R = Rx(roll) @ Ry(pitch) @ Rz(yaw), row-major. At the zero pose this
        // is exactly identity (with signed zeros), so v = points bit-exact.
        S[0] = cp * cy;                S[1] = -(cp * sy);             S[2] = sp;
        S[3] = cr * sy + sr * sp * cy; S[4] = cr * cy - sr * sp * sy; S[5] = -(sr * cp);
        S[6] = sr * sy - cr * sp * cy; S[7] = sr * cy + cr * sp * sy; S[8] = cr * cp;
        S[9] = *x; S[10] = *y; S[11] = *z;
    }
    __syncthreads();

    const float R0 = S[0], R1 = S[1], R2 = S[2];
    const float R3 = S[3], R4 = S[4], R5 = S[5];
    const float R6 = S[6], R7 = S[7], R8 = S[8];
    const float t0 = S[9], t1 = S[10], t2 = S[11];

    // Thread t owns floats [12t, 12t+12) of the block = same mapping as R5/R6,
    // so cnt/out are bit-identical.
    const float4* pv = (const float4*)((const float*)st + t * 12);
    float4 q0 = pv[0];
    float4 q1 = pv[1];
    float4 q2 = pv[2];

    int cnt = 0;
    auto proc = [&](float px, float py, float pz, float& ox, float& oy, float& oz) {
        float d0 = px - t0, d1 = py - t1, d2 = pz - t2;
        // ascending-k fma accumulation to match the numpy reference's matmul
        float v0 = fmaf(d2, R6, fmaf(d1, R3, d0 * R0));
        float v1 = fmaf(d2, R7, fmaf(d1, R4, d0 * R1));
        float v2 = fmaf(d2, R8, fmaf(d1, R5, d0 * R2));
        float p0 = fmaf(v2, CXC, v0 * FX);
        float p1 = fmaf(v2, CYC, v1 * FY);
        float u = p0 / v2;           // IEEE div; inf/nan on v2==0 compares false, same as numpy mask
        float w = p1 / v2;
        bool fov = (v2 > 0.0f) && (u > 1.0f) && (u < U_MAX) && (w > 1.0f) && (w < W_MAX);
        if (fov && (v2 > MIN_D) && (v2 < MAX_D_R)) cnt++;
        bool m = fov && (v2 > MIN_D) && (v2 < MAX_D_M);
        ox = m ? v0 : 0.0f;
        oy = m ? v1 : 0.0f;
        oz = m ? v2 : 0.0f;
    };

    float4 o0, o1, o2;
    proc(q0.x, q0.y, q0.z, o0.x, o0.y, o0.z);   // point 0
    proc(q0.w, q1.x, q1.y, o0.w, o1.x, o1.y);   // point 1
    proc(q1.z, q1.w, q2.x, o1.z, o1.w, o2.x);   // point 2
    proc(q2.y, q2.z, q2.w, o2.y, o2.z, o2.w);   // point 3

    // In-place writeback of my own 48B region (no cross-thread hazard).
    float4* wv = (float4*)((float*)st + t * 12);
    wv[0] = o0;
    wv[1] = o1;
    wv[2] = o2;
    __syncthreads();

    // Coalesced stage-out: 3 full-line 1KB wave stores (plain cached).
    out[gbase + t]       = st[t];
    out[gbase + t + 256] = st[t + 256];
    out[gbase + t + 512] = st[t + 512];

    // wave reduce (wave = 64), block reduce in LDS, ONE PLAIN STORE per block
    // into its own slot (no atomics; ws poisoned each call so write always).
    for (int off = 32; off > 0; off >>= 1) cnt += __shfl_down(cnt, off, 64);
    __shared__ int red[4];
    const int wave = threadIdx.x >> 6;
    if ((threadIdx.x & 63) == 0) red[wave] = cnt;
    __syncthreads();
    if (threadIdx.x == 0) {
        ((unsigned int*)ws)[16 + blockIdx.x] =
            (unsigned int)(red[0] + red[1] + red[2] + red[3]);
    }
}

__global__ void finalize_kernel(const float* __restrict__ ws, float* __restrict__ out) {
    const unsigned int* slots = (const unsigned int*)ws + 16;
    unsigned int c = 0;
    for (int i = threadIdx.x; i < BLOCKS; i += 256) c += slots[i];
    for (int off = 32; off > 0; off >>= 1) c += __shfl_down(c, off, 64);
    __shared__ unsigned int red[4];
    const int wave = threadIdx.x >> 6;
    if ((threadIdx.x & 63) == 0) red[wave] = c;
    __syncthreads();
    if (threadIdx.x == 0) {
        unsigned int tot = red[0] + red[1] + red[2] + red[3];
        out[(long)3 * N_PTS] = 1.0f / ((float)tot + 1e-6f);
    }
}

extern "C" void kernel_launch(void* const* d_in, const int* in_sizes, int n_in,
                              void* d_out, int out_size, void* d_ws, size_t ws_size,
                              hipStream_t stream) {
    const float* points = (const float*)d_in[0];
    const float* x      = (const float*)d_in[1];
    const float* y      = (const float*)d_in[2];
    const float* z      = (const float*)d_in[3];
    const float* roll   = (const float*)d_in[4];
    const float* pitch  = (const float*)d_in[5];
    const float* yaw    = (const float*)d_in[6];
    float* ws = (float*)d_ws;
    float* out = (float*)d_out;

    frustum_kernel<<<BLOCKS, THREADS, 0, stream>>>((const float4*)points,
                                                   x, y, z, roll, pitch, yaw,
                                                   ws, (float4*)out);
    finalize_kernel<<<1, 256, 0, stream>>>(ws, out);
}

// Round 12
// 186.857 us; speedup vs baseline: 1.1227x; 1.0527x over previous
//
#include <hip/hip_runtime.h>

// Problem constants (from reference)
#define N_PTS 8388608
#define FX 758.03967f
#define CXC 621.46572f
#define FY 761.62359f
#define CYC 756.86402f
#define U_MAX 1231.0f   // WIDTH - 1
#define W_MAX 1615.0f   // HEIGHT - 1
#define MIN_D 1.0f
#define MAX_D_R 10.0f
#define MAX_D_M 5.0f

#define THREADS 256
#define BLOCKS (N_PTS / 1024)    // 1024 points per block -> 8192 blocks

typedef float nfloat4 __attribute__((ext_vector_type(4)));

// Workspace layout (uints): [16 + b] (b in [0,BLOCKS)) = per-block partial
// count, PLAIN STORE (no atomics, no zero-init -> no init kernel needed).
//
// Evidence ledger (frustum dur / hbm_bytes / eff BW):
//  R5 strided x3:    62.0 / 152MB / 2.45    R6 LDS-coalesced: 58.5 / 151 / 2.59
//  R7 strided x6:    86.8 / 209MB / 2.41    R8 R6+nt stores:  59.6 / 151 / 2.54
//  R9 R6 depth x2:   60.3 / 151MB / 2.51    R10 persistent:   77.5 / 203 / 2.62
//  R11 R6+fused pose/slots: 60.5 / 151MB / 2.49  (2-kernel structure verified)
//  => SIX structural levers null/negative; every variant streams at 2.4-2.6
//     TB/s while copy ubench = 6.3 and harness fills = 6.8. Stall audit (R11):
//     ~7us/block of memory-wait vs 0.75us fair HBM share -- latency/queueing,
//     not bytes. All throughput pipes <25% busy.
//  THIS ROUND (last untested axis): READ-side cache policy. points is
//  read-once per dispatch; its L2 allocation churns 32MB of L2 and evicts
//  not-yet-drained write lines (read/write L2 contention theory for the 2.5
//  pin). nt loads = single variable on the R11 base.
//  R3: nt on 48B-strided STORES amplified WRITE 1.74x (stride interaction).
//  R4: fused finalize w/ __threadfence+ticket serialized everything (571us).

__global__ __launch_bounds__(256) void frustum_kernel(const float4* __restrict__ pts,
                                                      const float* __restrict__ x,
                                                      const float* __restrict__ y,
                                                      const float* __restrict__ z,
                                                      const float* __restrict__ roll,
                                                      const float* __restrict__ pitch,
                                                      const float* __restrict__ yaw,
                                                      float* __restrict__ ws,
                                                      float4* __restrict__ out) {
    // 256 threads x 4 points = 1024 points = 768 float4 = 12 KB per block.
    __shared__ float4 st[768];
    __shared__ float S[12];

    const int t = threadIdx.x;
    const long gbase = (long)blockIdx.x * 768;   // block's first float4 index

    // Coalesced stage-in, NONTEMPORAL loads: points is read-once per dispatch,
    // so skip L2 allocation -> dedicate L2 to the write stream (contention
    // theory). Values are bit-identical to cached loads.
    const nfloat4* npts = (const nfloat4*)pts;
    nfloat4 a0 = __builtin_nontemporal_load(&npts[gbase + t]);
    nfloat4 a1 = __builtin_nontemporal_load(&npts[gbase + t + 256]);
    nfloat4 a2 = __builtin_nontemporal_load(&npts[gbase + t + 512]);
    st[t]       = *(const float4*)&a0;
    st[t + 256] = *(const float4*)&a1;
    st[t + 512] = *(const float4*)&a2;

    // Per-block pose setup (bit-identical expressions; R10/R11-verified).
    if (t == 0) {
        float cr = cosf(*roll), sr = sinf(*roll);
        float cp = cosf(*pitch), sp = sinf(*pitch);
        float cy = cosf(*yaw),  sy = sinf(*yaw);
        // R = Rx(roll) @ Ry(pitch) @ Rz(yaw), row-major. At the zero pose this
        // is exactly identity (with signed zeros), so v = points bit-exact.
        S[0] = cp * cy;                S[1] = -(cp * sy);             S[2] = sp;
        S[3] = cr * sy + sr * sp * cy; S[4] = cr * cy - sr * sp * sy; S[5] = -(sr * cp);
        S[6] = sr * sy - cr * sp * cy; S[7] = sr * cy + cr * sp * sy; S[8] = cr * cp;
        S[9] = *x; S[10] = *y; S[11] = *z;
    }
    __syncthreads();

    const float R0 = S[0], R1 = S[1], R2 = S[2];
    const float R3 = S[3], R4 = S[4], R5 = S[5];
    const float R6 = S[6], R7 = S[7], R8 = S[8];
    const float t0 = S[9], t1 = S[10], t2 = S[11];

    // Thread t owns floats [12t, 12t+12) of the block = same mapping as R5/R6,
    // so cnt/out are bit-identical.
    const float4* pv = (const float4*)((const float*)st + t * 12);
    float4 q0 = pv[0];
    float4 q1 = pv[1];
    float4 q2 = pv[2];

    int cnt = 0;
    auto proc = [&](float px, float py, float pz, float& ox, float& oy, float& oz) {
        float d0 = px - t0, d1 = py - t1, d2 = pz - t2;
        // ascending-k fma accumulation to match the numpy reference's matmul
        float v0 = fmaf(d2, R6, fmaf(d1, R3, d0 * R0));
        float v1 = fmaf(d2, R7, fmaf(d1, R4, d0 * R1));
        float v2 = fmaf(d2, R8, fmaf(d1, R5, d0 * R2));
        float p0 = fmaf(v2, CXC, v0 * FX);
        float p1 = fmaf(v2, CYC, v1 * FY);
        float u = p0 / v2;           // IEEE div; inf/nan on v2==0 compares false, same as numpy mask
        float w = p1 / v2;
        bool fov = (v2 > 0.0f) && (u > 1.0f) && (u < U_MAX) && (w > 1.0f) && (w < W_MAX);
        if (fov && (v2 > MIN_D) && (v2 < MAX_D_R)) cnt++;
        bool m = fov && (v2 > MIN_D) && (v2 < MAX_D_M);
        ox = m ? v0 : 0.0f;
        oy = m ? v1 : 0.0f;
        oz = m ? v2 : 0.0f;
    };

    float4 o0, o1, o2;
    proc(q0.x, q0.y, q0.z, o0.x, o0.y, o0.z);   // point 0
    proc(q0.w, q1.x, q1.y, o0.w, o1.x, o1.y);   // point 1
    proc(q1.z, q1.w, q2.x, o1.z, o1.w, o2.x);   // point 2
    proc(q2.y, q2.z, q2.w, o2.y, o2.z, o2.w);   // point 3

    // In-place writeback of my own 48B region (no cross-thread hazard).
    float4* wv = (float4*)((float*)st + t * 12);
    wv[0] = o0;
    wv[1] = o1;
    wv[2] = o2;
    __syncthreads();

    // Coalesced stage-out: 3 full-line 1KB wave stores (plain cached;
    // R8 proved nt stores neutral, keep the simpler verified config).
    out[gbase + t]       = st[t];
    out[gbase + t + 256] = st[t + 256];
    out[gbase + t + 512] = st[t + 512];

    // wave reduce (wave = 64), block reduce in LDS, ONE PLAIN STORE per block
    // into its own slot (no atomics; ws poisoned each call so write always).
    for (int off = 32; off > 0; off >>= 1) cnt += __shfl_down(cnt, off, 64);
    __shared__ int red[4];
    const int wave = threadIdx.x >> 6;
    if ((threadIdx.x & 63) == 0) red[wave] = cnt;
    __syncthreads();
    if (threadIdx.x == 0) {
        ((unsigned int*)ws)[16 + blockIdx.x] =
            (unsigned int)(red[0] + red[1] + red[2] + red[3]);
    }
}

__global__ void finalize_kernel(const float* __restrict__ ws, float* __restrict__ out) {
    const unsigned int* slots = (const unsigned int*)ws + 16;
    unsigned int c = 0;
    for (int i = threadIdx.x; i < BLOCKS; i += 256) c += slots[i];
    for (int off = 32; off > 0; off >>= 1) c += __shfl_down(c, off, 64);
    __shared__ unsigned int red[4];
    const int wave = threadIdx.x >> 6;
    if ((threadIdx.x & 63) == 0) red[wave] = c;
    __syncthreads();
    if (threadIdx.x == 0) {
        unsigned int tot = red[0] + red[1] + red[2] + red[3];
        out[(long)3 * N_PTS] = 1.0f / ((float)tot + 1e-6f);
    }
}

extern "C" void kernel_launch(void* const* d_in, const int* in_sizes, int n_in,
                              void* d_out, int out_size, void* d_ws, size_t ws_size,
                              hipStream_t stream) {
    const float* points = (const float*)d_in[0];
    const float* x      = (const float*)d_in[1];
    const float* y      = (const float*)d_in[2];
    const float* z      = (const float*)d_in[3];
    const float* roll   = (const float*)d_in[4];
    const float* pitch  = (const float*)d_in[5];
    const float* yaw    = (const float*)d_in[6];
    float* ws = (float*)d_ws;
    float* out = (float*)d_out;

    frustum_kernel<<<BLOCKS, THREADS, 0, stream>>>((const float4*)points,
                                                   x, y, z, roll, pitch, yaw,
                                                   ws, (float4*)out);
    finalize_kernel<<<1, 256, 0, stream>>>(ws, out);
}

// Round 13
// 186.368 us; speedup vs baseline: 1.1256x; 1.0026x over previous
//
#include <hip/hip_runtime.h>

// Problem constants (from reference)
#define N_PTS 8388608
#define FX 758.03967f
#define CXC 621.46572f
#define FY 761.62359f
#define CYC 756.86402f
#define U_MAX 1231.0f   // WIDTH - 1
#define W_MAX 1615.0f   // HEIGHT - 1
#define MIN_D 1.0f
#define MAX_D_R 10.0f
#define MAX_D_M 5.0f

#define THREADS 256
#define BLOCKS (N_PTS / 1024)    // 1024 points per block -> 8192 blocks

typedef float nfloat4 __attribute__((ext_vector_type(4)));

// Workspace layout (uints): [16 + b] (b in [0,BLOCKS)) = per-block partial
// count, PLAIN STORE (no atomics, no zero-init -> no init kernel needed).
//
// Evidence ledger (frustum dur / hbm_bytes / eff BW):
//  R5 strided x3:    62.0 / 152MB / 2.45    R6 LDS-coalesced: 58.5 / 151 / 2.59
//  R7 strided x6:    86.8 / 209MB / 2.41    R8 R6+nt stores:  59.6 / 151 / 2.54
//  R9 R6 depth x2:   60.3 / 151MB / 2.51    R10 persistent:   77.5 / 203 / 2.62
//  R11 R6+fused pose/slots: 60.5 / 151MB / 2.49
//  R12 R11+NT LOADS: total 196.7 -> 186.9 (-10us, 3x noise); frustum fell OUT
//      of top-5 (<59us, ~50us by decomposition, ~3.0 TB/s). The 2.5 TB/s pin
//      was L2 read/write contention: read-once `points` allocating in L2
//      evicted/contended with undrained write lines. nt loads fixed it.
//  THIS ROUND: complete the 2x2 -- nt loads + NT STORES. Stores are full-line
//  1KB bursts (nothing for L2 to merge); skipping the L2 allocate/evict
//  round-trip is how the 6.8 TB/s fill kernel streams. R8 proved nt stores on
//  THESE coalesced stores keep WRITE clean (98.6MB); R3's 1.74x amplification
//  was the nt x 48B-stride interaction only.
//  R4: fused finalize w/ __threadfence+ticket serialized everything (571us).

__global__ __launch_bounds__(256) void frustum_kernel(const float4* __restrict__ pts,
                                                      const float* __restrict__ x,
                                                      const float* __restrict__ y,
                                                      const float* __restrict__ z,
                                                      const float* __restrict__ roll,
                                                      const float* __restrict__ pitch,
                                                      const float* __restrict__ yaw,
                                                      float* __restrict__ ws,
                                                      float4* __restrict__ out) {
    // 256 threads x 4 points = 1024 points = 768 float4 = 12 KB per block.
    __shared__ float4 st[768];
    __shared__ float S[12];

    const int t = threadIdx.x;
    const long gbase = (long)blockIdx.x * 768;   // block's first float4 index

    // Coalesced stage-in, NONTEMPORAL loads (R12-verified win): read-once
    // points skips L2 allocation -> no contention with the write stream.
    const nfloat4* npts = (const nfloat4*)pts;
    nfloat4 a0 = __builtin_nontemporal_load(&npts[gbase + t]);
    nfloat4 a1 = __builtin_nontemporal_load(&npts[gbase + t + 256]);
    nfloat4 a2 = __builtin_nontemporal_load(&npts[gbase + t + 512]);
    st[t]       = *(const float4*)&a0;
    st[t + 256] = *(const float4*)&a1;
    st[t + 512] = *(const float4*)&a2;

    // Per-block pose setup (bit-identical expressions; R10/R11-verified).
    if (t == 0) {
        float cr = cosf(*roll), sr = sinf(*roll);
        float cp = cosf(*pitch), sp = sinf(*pitch);
        float cy = cosf(*yaw),  sy = sinf(*yaw);
        // R = Rx(roll) @ Ry(pitch) @ Rz(yaw), row-major. At the zero pose this
        // is exactly identity (with signed zeros), so v = points bit-exact.
        S[0] = cp * cy;                S[1] = -(cp * sy);             S[2] = sp;
        S[3] = cr * sy + sr * sp * cy; S[4] = cr * cy - sr * sp * sy; S[5] = -(sr * cp);
        S[6] = sr * sy - cr * sp * cy; S[7] = sr * cy + cr * sp * sy; S[8] = cr * cp;
        S[9] = *x; S[10] = *y; S[11] = *z;
    }
    __syncthreads();

    const float R0 = S[0], R1 = S[1], R2 = S[2];
    const float R3 = S[3], R4 = S[4], R5 = S[5];
    const float R6 = S[6], R7 = S[7], R8 = S[8];
    const float t0 = S[9], t1 = S[10], t2 = S[11];

    // Thread t owns floats [12t, 12t+12) of the block = same mapping as R5/R6,
    // so cnt/out are bit-identical.
    const float4* pv = (const float4*)((const float*)st + t * 12);
    float4 q0 = pv[0];
    float4 q1 = pv[1];
    float4 q2 = pv[2];

    int cnt = 0;
    auto proc = [&](float px, float py, float pz, float& ox, float& oy, float& oz) {
        float d0 = px - t0, d1 = py - t1, d2 = pz - t2;
        // ascending-k fma accumulation to match the numpy reference's matmul
        float v0 = fmaf(d2, R6, fmaf(d1, R3, d0 * R0));
        float v1 = fmaf(d2, R7, fmaf(d1, R4, d0 * R1));
        float v2 = fmaf(d2, R8, fmaf(d1, R5, d0 * R2));
        float p0 = fmaf(v2, CXC, v0 * FX);
        float p1 = fmaf(v2, CYC, v1 * FY);
        float u = p0 / v2;           // IEEE div; inf/nan on v2==0 compares false, same as numpy mask
        float w = p1 / v2;
        bool fov = (v2 > 0.0f) && (u > 1.0f) && (u < U_MAX) && (w > 1.0f) && (w < W_MAX);
        if (fov && (v2 > MIN_D) && (v2 < MAX_D_R)) cnt++;
        bool m = fov && (v2 > MIN_D) && (v2 < MAX_D_M);
        ox = m ? v0 : 0.0f;
        oy = m ? v1 : 0.0f;
        oz = m ? v2 : 0.0f;
    };

    float4 o0, o1, o2;
    proc(q0.x, q0.y, q0.z, o0.x, o0.y, o0.z);   // point 0
    proc(q0.w, q1.x, q1.y, o0.w, o1.x, o1.y);   // point 1
    proc(q1.z, q1.w, q2.x, o1.z, o1.w, o2.x);   // point 2
    proc(q2.y, q2.z, q2.w, o2.y, o2.z, o2.w);   // point 3

    // In-place writeback of my own 48B region (no cross-thread hazard).
    float4* wv = (float4*)((float*)st + t * 12);
    wv[0] = o0;
    wv[1] = o1;
    wv[2] = o2;
    __syncthreads();

    // Coalesced stage-out, NONTEMPORAL: full-line 1KB bursts stream straight
    // to HBM (fill-kernel style), skipping the L2 allocate/evict round-trip.
    // R8 verified WRITE_SIZE stays clean (98.6MB) for nt on these stores.
    float4 s0 = st[t];
    float4 s1 = st[t + 256];
    float4 s2 = st[t + 512];
    __builtin_nontemporal_store(*(const nfloat4*)&s0, (nfloat4*)&out[gbase + t]);
    __builtin_nontemporal_store(*(const nfloat4*)&s1, (nfloat4*)&out[gbase + t + 256]);
    __builtin_nontemporal_store(*(const nfloat4*)&s2, (nfloat4*)&out[gbase + t + 512]);

    // wave reduce (wave = 64), block reduce in LDS, ONE PLAIN STORE per block
    // into its own slot (no atomics; ws poisoned each call so write always).
    for (int off = 32; off > 0; off >>= 1) cnt += __shfl_down(cnt, off, 64);
    __shared__ int red[4];
    const int wave = threadIdx.x >> 6;
    if ((threadIdx.x & 63) == 0) red[wave] = cnt;
    __syncthreads();
    if (threadIdx.x == 0) {
        ((unsigned int*)ws)[16 + blockIdx.x] =
            (unsigned int)(red[0] + red[1] + red[2] + red[3]);
    }
}

__global__ void finalize_kernel(const float* __restrict__ ws, float* __restrict__ out) {
    const unsigned int* slots = (const unsigned int*)ws + 16;
    unsigned int c = 0;
    for (int i = threadIdx.x; i < BLOCKS; i += 256) c += slots[i];
    for (int off = 32; off > 0; off >>= 1) c += __shfl_down(c, off, 64);
    __shared__ unsigned int red[4];
    const int wave = threadIdx.x >> 6;
    if ((threadIdx.x & 63) == 0) red[wave] = c;
    __syncthreads();
    if (threadIdx.x == 0) {
        unsigned int tot = red[0] + red[1] + red[2] + red[3];
        out[(long)3 * N_PTS] = 1.0f / ((float)tot + 1e-6f);
    }
}

extern "C" void kernel_launch(void* const* d_in, const int* in_sizes, int n_in,
                              void* d_out, int out_size, void* d_ws, size_t ws_size,
                              hipStream_t stream) {
    const float* points = (const float*)d_in[0];
    const float* x      = (const float*)d_in[1];
    const float* y      = (const float*)d_in[2];
    const float* z      = (const float*)d_in[3];
    const float* roll   = (const float*)d_in[4];
    const float* pitch  = (const float*)d_in[5];
    const float* yaw    = (const float*)d_in[6];
    float* ws = (float*)d_ws;
    float* out = (float*)d_out;

    frustum_kernel<<<BLOCKS, THREADS, 0, stream>>>((const float4*)points,
                                                   x, y, z, roll, pitch, yaw,
                                                   ws, (float4*)out);
    finalize_kernel<<<1, 256, 0, stream>>>(ws, out);
}